// Round 1
// baseline (1550.362 us; speedup 1.0000x reference)
//
#include <hip/hip_runtime.h>
#include <hip/hip_bf16.h>
#include <math.h>

// Problem constants
#define B_SZ 8
#define N_SZ 4096
#define C_SZ 128
#define K_SZ 16
#define NPOINT 1024            // N / POOL_RATE
#define FPS_THREADS 1024
#define PPT 4                  // points per thread = N / FPS_THREADS

// ---------------------------------------------------------------------------
// Kernel 1: transpose feature_map (B, C, N) -> fmT (B*N, C)
// ---------------------------------------------------------------------------
__global__ void transpose_fm(const float* __restrict__ fm, float* __restrict__ fmT) {
    __shared__ float tile[32][33];
    const int b  = blockIdx.z;
    const int c0 = blockIdx.y * 32;
    const int n0 = blockIdx.x * 32;
    const int tx = threadIdx.x;   // 0..31
    const int ty = threadIdx.y;   // 0..7
    const float* p = fm + (size_t)b * C_SZ * N_SZ;
#pragma unroll
    for (int i = 0; i < 4; i++) {
        tile[ty + i * 8][tx] = p[(size_t)(c0 + ty + i * 8) * N_SZ + n0 + tx];
    }
    __syncthreads();
    float* q = fmT + (size_t)b * N_SZ * C_SZ;
#pragma unroll
    for (int i = 0; i < 4; i++) {
        q[(size_t)(n0 + ty + i * 8) * C_SZ + c0 + tx] = tile[tx][ty + i * 8];
    }
}

// ---------------------------------------------------------------------------
// Kernel 2: farthest point sampling, one block per batch.
// Bit-exact replication of the numpy/JAX scan:
//   emit far; dist = (x-cx)^2+(y-cy)^2+(z-cz)^2 (strict IEEE, no FMA, sum
//   order ((x+y)+z)); distance = min(distance, dist); far = first-argmax.
// Writes cents (B,NPOINT) and vertices_pool (B,3,NPOINT) directly.
// ---------------------------------------------------------------------------
__global__ __launch_bounds__(FPS_THREADS) void fps_kernel(
        const float* __restrict__ verts,   // (B, 3, N)
        float* __restrict__ out_vp,        // (B, 3, NPOINT)
        int* __restrict__ cents)           // (B, NPOINT)
{
    __shared__ float sx[N_SZ], sy[N_SZ], sz[N_SZ];
    __shared__ float swv[16];
    __shared__ int   swi[16];
    __shared__ float scx, scy, scz;
    __shared__ int   scidx;

    const int b   = blockIdx.x;
    const int tid = threadIdx.x;
    const int lane = tid & 63;
    const int wid  = tid >> 6;

    const float* vb = verts + (size_t)b * 3 * N_SZ;

    float px[PPT], py[PPT], pz[PPT], dist[PPT];
#pragma unroll
    for (int j = 0; j < PPT; j++) {
        const int n = tid + j * FPS_THREADS;
        const float x = vb[n];
        const float y = vb[N_SZ + n];
        const float z = vb[2 * N_SZ + n];
        px[j] = x; py[j] = y; pz[j] = z;
        sx[n] = x; sy[n] = y; sz[n] = z;
        dist[j] = 1e10f;
    }
    if (tid == 0) { scidx = 0; scx = vb[0]; scy = vb[N_SZ]; scz = vb[2 * N_SZ]; }
    __syncthreads();

    for (int i = 0; i < NPOINT; i++) {
        const float cx = scx, cy = scy, cz = scz;
        const int ci = scidx;
        if (tid == 0) {
            cents[b * NPOINT + i] = ci;
            out_vp[(b * 3 + 0) * NPOINT + i] = cx;
            out_vp[(b * 3 + 1) * NPOINT + i] = cy;
            out_vp[(b * 3 + 2) * NPOINT + i] = cz;
        }

        float bv = -1.0f;
        int   bi = 0;
#pragma unroll
        for (int j = 0; j < PPT; j++) {
            const float dx = __fsub_rn(px[j], cx);
            const float dy = __fsub_rn(py[j], cy);
            const float dz = __fsub_rn(pz[j], cz);
            const float s  = __fadd_rn(__fadd_rn(__fmul_rn(dx, dx), __fmul_rn(dy, dy)),
                                       __fmul_rn(dz, dz));
            const float d  = fminf(dist[j], s);
            dist[j] = d;
            // strictly-greater keeps the lowest index (j ascending => index ascending)
            if (d > bv) { bv = d; bi = tid + j * FPS_THREADS; }
        }

        // wave-level butterfly argmax (value desc, index asc on ties)
#pragma unroll
        for (int off = 32; off >= 1; off >>= 1) {
            const float ov = __shfl_xor(bv, off, 64);
            const int   oi = __shfl_xor(bi, off, 64);
            if (ov > bv || (ov == bv && oi < bi)) { bv = ov; bi = oi; }
        }
        if (lane == 0) { swv[wid] = bv; swi[wid] = bi; }
        __syncthreads();

        if (wid == 0) {
            float v = (lane < 16) ? swv[lane] : -1.0f;
            int   ii = (lane < 16) ? swi[lane] : 0x7fffffff;
#pragma unroll
            for (int off = 8; off >= 1; off >>= 1) {
                const float ov = __shfl_xor(v, off, 64);
                const int   oi = __shfl_xor(ii, off, 64);
                if (ov > v || (ov == v && oi < ii)) { v = ov; ii = oi; }
            }
            if (lane == 0) {
                scidx = ii;
                scx = sx[ii]; scy = sy[ii]; scz = sz[ii];
            }
        }
        __syncthreads();
    }
}

// ---------------------------------------------------------------------------
// Kernel 3: gather+maxpool only the selected rows.
// One wave per output point; 64 lanes x float2 = 128 channels.
// pooled scratch layout: (B*NPOINT, C) row-major (coalesced stores).
// ---------------------------------------------------------------------------
__global__ __launch_bounds__(256) void pool_gather(
        const float* __restrict__ fmT,     // (B*N, C)
        const int* __restrict__ idx,       // (B*N*K), values in [0, B*N)
        const int* __restrict__ cents,     // (B*NPOINT)
        float* __restrict__ pooled)        // (B*NPOINT, C)
{
    const int wave = (int)((blockIdx.x * blockDim.x + threadIdx.x) >> 6);
    const int lane = threadIdx.x & 63;
    const int b = wave >> 10;          // NPOINT = 1024
    const int ci = cents[wave];
    const int* ip = idx + ((size_t)(b * N_SZ + ci)) * K_SZ;
    const float2* src = (const float2*)fmT;

    float2 acc = make_float2(-INFINITY, -INFINITY);
#pragma unroll
    for (int k = 0; k < K_SZ; k++) {
        const int p = ip[k];
        const float2 v = src[(size_t)p * (C_SZ / 2) + lane];
        acc.x = fmaxf(acc.x, v.x);
        acc.y = fmaxf(acc.y, v.y);
    }
    ((float2*)pooled)[(size_t)wave * (C_SZ / 2) + lane] = acc;
}

// ---------------------------------------------------------------------------
// Kernel 4: transpose pooled (B, NPOINT, C) -> out feature part (B, C, NPOINT)
// ---------------------------------------------------------------------------
__global__ void transpose_pooled(const float* __restrict__ pooled, float* __restrict__ out_fp) {
    __shared__ float tile[32][33];
    const int b  = blockIdx.z;
    const int c0 = blockIdx.y * 32;
    const int j0 = blockIdx.x * 32;
    const int tx = threadIdx.x;
    const int ty = threadIdx.y;
    const float* p = pooled + (size_t)b * NPOINT * C_SZ;
#pragma unroll
    for (int i = 0; i < 4; i++) {
        tile[ty + i * 8][tx] = p[(size_t)(j0 + ty + i * 8) * C_SZ + c0 + tx];
    }
    __syncthreads();
    float* q = out_fp + (size_t)b * C_SZ * NPOINT;
#pragma unroll
    for (int i = 0; i < 4; i++) {
        q[(size_t)(c0 + ty + i * 8) * NPOINT + j0 + tx] = tile[tx][ty + i * 8];
    }
}

// ---------------------------------------------------------------------------
extern "C" void kernel_launch(void* const* d_in, const int* in_sizes, int n_in,
                              void* d_out, int out_size, void* d_ws, size_t ws_size,
                              hipStream_t stream) {
    const float* verts = (const float*)d_in[0];   // (B,3,N) f32
    const float* fm    = (const float*)d_in[1];   // (B,C,N) f32
    const int*   idx   = (const int*)d_in[2];     // (B*N*K) i32

    float* out    = (float*)d_out;
    float* out_vp = out;                               // B*3*NPOINT = 24576
    float* out_fp = out + (size_t)B_SZ * 3 * NPOINT;   // B*C*NPOINT

    char* ws = (char*)d_ws;
    float* fmT    = (float*)ws;                                          // 16 MB
    float* pooled = (float*)(ws + (size_t)B_SZ * N_SZ * C_SZ * 4);       //  4 MB
    int*   cents  = (int*)(ws + (size_t)B_SZ * N_SZ * C_SZ * 4
                              + (size_t)B_SZ * NPOINT * C_SZ * 4);       // 32 KB

    dim3 tb(32, 8);
    transpose_fm<<<dim3(N_SZ / 32, C_SZ / 32, B_SZ), tb, 0, stream>>>(fm, fmT);
    fps_kernel<<<B_SZ, FPS_THREADS, 0, stream>>>(verts, out_vp, cents);
    pool_gather<<<(B_SZ * NPOINT) / 4, 256, 0, stream>>>(fmT, idx, cents, pooled);
    transpose_pooled<<<dim3(NPOINT / 32, C_SZ / 32, B_SZ), tb, 0, stream>>>(pooled, out_fp);
}

// Round 2
// 736.889 us; speedup vs baseline: 2.1039x; 2.1039x over previous
//
#include <hip/hip_runtime.h>
#include <hip/hip_bf16.h>
#include <math.h>

// Problem constants
#define B_SZ 8
#define N_SZ 4096
#define C_SZ 128
#define K_SZ 16
#define NPOINT 1024            // N / POOL_RATE

// FPS config: 256 threads (4 waves), 16 points per thread
#define FPS_T 256
#define FPS_PAIRS 8            // 8 float2-pairs = 16 points per thread

typedef float vf2 __attribute__((ext_vector_type(2)));

// ---------------------------------------------------------------------------
// DPP wave64 reductions (VALU-latency, no LDS):
//   row_shr:1/2/4/8 reduce within rows of 16; row_bcast:15/31 combine rows.
//   Result in lane 63, broadcast via readlane.
// ---------------------------------------------------------------------------
template <int CTRL>
__device__ __forceinline__ float dpp_fmax(float x) {
    int t = __builtin_amdgcn_update_dpp(0, __float_as_int(x), CTRL, 0xF, 0xF, true);
    return fmaxf(x, __int_as_float(t));   // identity 0 ok: values are >= 0
}
template <int CTRL>
__device__ __forceinline__ unsigned dpp_umin(unsigned x) {
    unsigned t = (unsigned)__builtin_amdgcn_update_dpp((int)0xFFFFFFFF, (int)x,
                                                       CTRL, 0xF, 0xF, false);
    return t < x ? t : x;                 // invalid lanes read old = UINT_MAX
}
__device__ __forceinline__ float wave_fmax(float x) {
    x = dpp_fmax<0x111>(x);  // row_shr:1
    x = dpp_fmax<0x112>(x);  // row_shr:2
    x = dpp_fmax<0x114>(x);  // row_shr:4
    x = dpp_fmax<0x118>(x);  // row_shr:8
    x = dpp_fmax<0x142>(x);  // row_bcast:15
    x = dpp_fmax<0x143>(x);  // row_bcast:31
    return __int_as_float(__builtin_amdgcn_readlane(__float_as_int(x), 63));
}
__device__ __forceinline__ unsigned wave_umin(unsigned x) {
    x = dpp_umin<0x111>(x);
    x = dpp_umin<0x112>(x);
    x = dpp_umin<0x114>(x);
    x = dpp_umin<0x118>(x);
    x = dpp_umin<0x142>(x);
    x = dpp_umin<0x143>(x);
    return (unsigned)__builtin_amdgcn_readlane((int)x, 63);
}

// ---------------------------------------------------------------------------
// Kernel 1: transpose feature_map (B, C, N) -> fmT (B*N, C)
// ---------------------------------------------------------------------------
__global__ void transpose_fm(const float* __restrict__ fm, float* __restrict__ fmT) {
    __shared__ float tile[32][33];
    const int b  = blockIdx.z;
    const int c0 = blockIdx.y * 32;
    const int n0 = blockIdx.x * 32;
    const int tx = threadIdx.x;   // 0..31
    const int ty = threadIdx.y;   // 0..7
    const float* p = fm + (size_t)b * C_SZ * N_SZ;
#pragma unroll
    for (int i = 0; i < 4; i++) {
        tile[ty + i * 8][tx] = p[(size_t)(c0 + ty + i * 8) * N_SZ + n0 + tx];
    }
    __syncthreads();
    float* q = fmT + (size_t)b * N_SZ * C_SZ;
#pragma unroll
    for (int i = 0; i < 4; i++) {
        q[(size_t)(n0 + ty + i * 8) * C_SZ + c0 + tx] = tile[tx][ty + i * 8];
    }
}

// ---------------------------------------------------------------------------
// Kernel 2: FPS, one block (256 threads, 4 waves) per batch.
// Bit-exact numpy semantics: d=((x-cx)^2+(y-cy)^2)+(z-cz)^2 per-op rounding
// (no FMA contraction, no reassoc), min then first-index argmax.
// Loop has exactly one __syncthreads; argmax via DPP; no global stores in
// the loop (results buffered in LDS, written in coalesced epilogue).
// ---------------------------------------------------------------------------
__global__ __launch_bounds__(FPS_T) void fps_kernel(
        const float* __restrict__ verts,   // (B, 3, N)
        float* __restrict__ out_vp,        // (B, 3, NPOINT)
        int* __restrict__ cents)           // (B, NPOINT)
{
#pragma clang fp contract(off)
#pragma clang fp reassociate(off)
    __shared__ vf2   sxy[N_SZ];            // 32 KB
    __shared__ float szz[N_SZ];            // 16 KB
    __shared__ int   scent[NPOINT];        //  4 KB
    __shared__ alignas(16) float cval[2][4];
    __shared__ alignas(16) int   cidx[2][4];

    const int b    = blockIdx.x;
    const int tid  = threadIdx.x;
    const int lane = tid & 63;
    const int wid  = tid >> 6;
    const float* vb = verts + (size_t)b * 3 * N_SZ;

    // pair p covers global points n0 = tid + 2p*256 and n1 = n0 + 256
    vf2 px[FPS_PAIRS], py[FPS_PAIRS], pz[FPS_PAIRS], dd[FPS_PAIRS];
#pragma unroll
    for (int p = 0; p < FPS_PAIRS; p++) {
        const int n0 = tid + (2 * p) * FPS_T;
        const int n1 = n0 + FPS_T;
        const float x0 = vb[n0],            x1 = vb[n1];
        const float y0 = vb[N_SZ + n0],     y1 = vb[N_SZ + n1];
        const float z0 = vb[2 * N_SZ + n0], z1 = vb[2 * N_SZ + n1];
        px[p] = (vf2){x0, x1};
        py[p] = (vf2){y0, y1};
        pz[p] = (vf2){z0, z1};
        dd[p] = (vf2){1e10f, 1e10f};
        sxy[n0] = (vf2){x0, y0}; szz[n0] = z0;
        sxy[n1] = (vf2){x1, y1}; szz[n1] = z1;
    }
    __syncthreads();

    int ci = 0;
    vf2 cxy = sxy[0];
    float cz = szz[0];

    for (int i = 0; i < NPOINT; i++) {
        if (tid == 0) scent[i] = ci;

        const vf2 cx2 = (vf2){cxy.x, cxy.x};
        const vf2 cy2 = (vf2){cxy.y, cxy.y};
        const vf2 cz2 = (vf2){cz, cz};

        float bv = -1.0f;
        int   bj = 0;
#pragma unroll
        for (int p = 0; p < FPS_PAIRS; p++) {
            const vf2 dx = px[p] - cx2;
            const vf2 dy = py[p] - cy2;
            const vf2 dz = pz[p] - cz2;
            vf2 s = dx * dx + dy * dy;   // contract off => mul,mul,add (exact)
            s = s + dz * dz;
            vf2 d;
            d.x = fminf(dd[p].x, s.x);
            d.y = fminf(dd[p].y, s.y);
            dd[p] = d;
            // strictly-greater keeps lowest index (j ascending => n ascending)
            if (d.x > bv) { bv = d.x; bj = 2 * p; }
            if (d.y > bv) { bv = d.y; bj = 2 * p + 1; }
        }
        const unsigned bn = (unsigned)(tid + (bj << 8));   // global point index

        // wave argmax: max value, then min index among value-holders
        const float    wmax = wave_fmax(bv);
        const unsigned cand = (bv == wmax) ? bn : 0xFFFFFFFFu;
        const unsigned widx = wave_umin(cand);

        const int par = i & 1;
        if (lane == 0) { cval[par][wid] = wmax; cidx[par][wid] = (int)widx; }
        __syncthreads();

        // all threads redundantly resolve the 4-way final (no 2nd barrier:
        // parity double-buffer makes the next write race-free)
        const float4 vv = *(const float4*)&cval[par][0];
        const int4   jj = *(const int4*)&cidx[par][0];
        float v = vv.x; int ii = jj.x;
        if (vv.y > v || (vv.y == v && jj.y < ii)) { v = vv.y; ii = jj.y; }
        if (vv.z > v || (vv.z == v && jj.z < ii)) { v = vv.z; ii = jj.z; }
        if (vv.w > v || (vv.w == v && jj.w < ii)) { v = vv.w; ii = jj.w; }

        ci  = ii;
        cxy = sxy[ii];
        cz  = szz[ii];
    }
    __syncthreads();

    // epilogue: coalesced writes of cents + vertices_pool
    for (int i = tid; i < NPOINT; i += FPS_T) {
        const int c = scent[i];
        const vf2 xy = sxy[c];
        const float z = szz[c];
        cents[b * NPOINT + i] = c;
        out_vp[(b * 3 + 0) * NPOINT + i] = xy.x;
        out_vp[(b * 3 + 1) * NPOINT + i] = xy.y;
        out_vp[(b * 3 + 2) * NPOINT + i] = z;
    }
}

// ---------------------------------------------------------------------------
// Kernel 3: gather+maxpool only the selected rows.
// One wave per output point; 64 lanes x float2 = 128 channels.
// ---------------------------------------------------------------------------
__global__ __launch_bounds__(256) void pool_gather(
        const float* __restrict__ fmT,     // (B*N, C)
        const int* __restrict__ idx,       // (B*N*K), values in [0, B*N)
        const int* __restrict__ cents,     // (B*NPOINT)
        float* __restrict__ pooled)        // (B*NPOINT, C)
{
    const int wave = (int)((blockIdx.x * blockDim.x + threadIdx.x) >> 6);
    const int lane = threadIdx.x & 63;
    const int b = wave >> 10;          // NPOINT = 1024
    const int ci = cents[wave];
    const int* ip = idx + ((size_t)(b * N_SZ + ci)) * K_SZ;
    const float2* src = (const float2*)fmT;

    float2 acc = make_float2(-INFINITY, -INFINITY);
#pragma unroll
    for (int k = 0; k < K_SZ; k++) {
        const int p = ip[k];
        const float2 v = src[(size_t)p * (C_SZ / 2) + lane];
        acc.x = fmaxf(acc.x, v.x);
        acc.y = fmaxf(acc.y, v.y);
    }
    ((float2*)pooled)[(size_t)wave * (C_SZ / 2) + lane] = acc;
}

// ---------------------------------------------------------------------------
// Kernel 4: transpose pooled (B, NPOINT, C) -> out feature part (B, C, NPOINT)
// ---------------------------------------------------------------------------
__global__ void transpose_pooled(const float* __restrict__ pooled, float* __restrict__ out_fp) {
    __shared__ float tile[32][33];
    const int b  = blockIdx.z;
    const int c0 = blockIdx.y * 32;
    const int j0 = blockIdx.x * 32;
    const int tx = threadIdx.x;
    const int ty = threadIdx.y;
    const float* p = pooled + (size_t)b * NPOINT * C_SZ;
#pragma unroll
    for (int i = 0; i < 4; i++) {
        tile[ty + i * 8][tx] = p[(size_t)(j0 + ty + i * 8) * C_SZ + c0 + tx];
    }
    __syncthreads();
    float* q = out_fp + (size_t)b * C_SZ * NPOINT;
#pragma unroll
    for (int i = 0; i < 4; i++) {
        q[(size_t)(c0 + ty + i * 8) * NPOINT + j0 + tx] = tile[tx][ty + i * 8];
    }
}

// ---------------------------------------------------------------------------
extern "C" void kernel_launch(void* const* d_in, const int* in_sizes, int n_in,
                              void* d_out, int out_size, void* d_ws, size_t ws_size,
                              hipStream_t stream) {
    const float* verts = (const float*)d_in[0];   // (B,3,N) f32
    const float* fm    = (const float*)d_in[1];   // (B,C,N) f32
    const int*   idx   = (const int*)d_in[2];     // (B*N*K) i32

    float* out    = (float*)d_out;
    float* out_vp = out;                               // B*3*NPOINT = 24576
    float* out_fp = out + (size_t)B_SZ * 3 * NPOINT;   // B*C*NPOINT

    char* ws = (char*)d_ws;
    float* fmT    = (float*)ws;                                          // 16 MB
    float* pooled = (float*)(ws + (size_t)B_SZ * N_SZ * C_SZ * 4);       //  4 MB
    int*   cents  = (int*)(ws + (size_t)B_SZ * N_SZ * C_SZ * 4
                              + (size_t)B_SZ * NPOINT * C_SZ * 4);       // 32 KB

    dim3 tb(32, 8);
    transpose_fm<<<dim3(N_SZ / 32, C_SZ / 32, B_SZ), tb, 0, stream>>>(fm, fmT);
    fps_kernel<<<B_SZ, FPS_T, 0, stream>>>(verts, out_vp, cents);
    pool_gather<<<(B_SZ * NPOINT) / 4, 256, 0, stream>>>(fmT, idx, cents, pooled);
    transpose_pooled<<<dim3(NPOINT / 32, C_SZ / 32, B_SZ), tb, 0, stream>>>(pooled, out_fp);
}

// Round 3
// 698.095 us; speedup vs baseline: 2.2208x; 1.0556x over previous
//
#include <hip/hip_runtime.h>
#include <hip/hip_bf16.h>
#include <math.h>

// Problem constants
#define B_SZ 8
#define N_SZ 4096
#define C_SZ 128
#define K_SZ 16
#define NPOINT 1024            // N / POOL_RATE

// FPS config: 512 threads (8 waves, 2 per SIMD), 8 points per thread
#define FPS_T 512
#define FPS_PAIRS 4            // 4 float2-pairs = 8 points per thread

typedef float vf2 __attribute__((ext_vector_type(2)));

// ---------------------------------------------------------------------------
// Wave64 argmax via a single u64-key DPP max chain.
// key = (dist_bits << 32) | (4095 - n): max key == max dist, min n on ties.
// dist >= 0 so float bits are monotone as u32. bound_ctrl=1 feeds 0 into
// invalid lanes; 0 never beats a real key except when equal (same decision).
// Result valid in lane 63.
// ---------------------------------------------------------------------------
template <int CTRL>
__device__ __forceinline__ unsigned long long dpp_kmax_step(unsigned long long k) {
    const unsigned lo = (unsigned)k;
    const unsigned hi = (unsigned)(k >> 32);
    const unsigned lo2 = (unsigned)__builtin_amdgcn_update_dpp(0, (int)lo, CTRL, 0xF, 0xF, true);
    const unsigned hi2 = (unsigned)__builtin_amdgcn_update_dpp(0, (int)hi, CTRL, 0xF, 0xF, true);
    const unsigned long long k2 = ((unsigned long long)hi2 << 32) | (unsigned long long)lo2;
    return (k2 > k) ? k2 : k;
}
__device__ __forceinline__ unsigned long long wave_kmax63(unsigned long long k) {
    k = dpp_kmax_step<0x111>(k);  // row_shr:1
    k = dpp_kmax_step<0x112>(k);  // row_shr:2
    k = dpp_kmax_step<0x114>(k);  // row_shr:4
    k = dpp_kmax_step<0x118>(k);  // row_shr:8
    k = dpp_kmax_step<0x142>(k);  // row_bcast:15
    k = dpp_kmax_step<0x143>(k);  // row_bcast:31
    return k;
}
__device__ __forceinline__ unsigned long long kmax2(unsigned long long a,
                                                   unsigned long long b) {
    return a > b ? a : b;
}

// ---------------------------------------------------------------------------
// Kernel 1: transpose feature_map (B, C, N) -> fmT (B*N, C)
// ---------------------------------------------------------------------------
__global__ void transpose_fm(const float* __restrict__ fm, float* __restrict__ fmT) {
    __shared__ float tile[32][33];
    const int b  = blockIdx.z;
    const int c0 = blockIdx.y * 32;
    const int n0 = blockIdx.x * 32;
    const int tx = threadIdx.x;   // 0..31
    const int ty = threadIdx.y;   // 0..7
    const float* p = fm + (size_t)b * C_SZ * N_SZ;
#pragma unroll
    for (int i = 0; i < 4; i++) {
        tile[ty + i * 8][tx] = p[(size_t)(c0 + ty + i * 8) * N_SZ + n0 + tx];
    }
    __syncthreads();
    float* q = fmT + (size_t)b * N_SZ * C_SZ;
#pragma unroll
    for (int i = 0; i < 4; i++) {
        q[(size_t)(n0 + ty + i * 8) * C_SZ + c0 + tx] = tile[tx][ty + i * 8];
    }
}

// ---------------------------------------------------------------------------
// Kernel 2: FPS, one block (512 threads, 8 waves) per batch.
// Bit-exact numpy semantics: d=((x-cx)^2+(y-cy)^2)+(z-cz)^2 per-op rounding
// (no FMA contraction, no reassoc), min then first-index argmax.
// One __syncthreads per iteration; u64-key DPP argmax; no global traffic in
// the loop (results buffered in LDS, written in a coalesced epilogue).
// ---------------------------------------------------------------------------
__global__ __launch_bounds__(FPS_T) void fps_kernel(
        const float* __restrict__ verts,   // (B, 3, N)
        float* __restrict__ out_vp,        // (B, 3, NPOINT)
        int* __restrict__ cents)           // (B, NPOINT)
{
#pragma clang fp contract(off)
#pragma clang fp reassociate(off)
    __shared__ float4 sp[N_SZ];                       // 64 KB xyz (w unused)
    __shared__ int    scent[NPOINT];                  //  4 KB
    __shared__ alignas(16) unsigned long long ckey[2][8];

    const int b    = blockIdx.x;
    const int tid  = threadIdx.x;
    const int lane = tid & 63;
    const int wid  = tid >> 6;
    const float* vb = verts + (size_t)b * 3 * N_SZ;

    // pair p covers global points n = tid + (2p)*512 and n + 512
    vf2 px[FPS_PAIRS], py[FPS_PAIRS], pz[FPS_PAIRS], dd[FPS_PAIRS];
#pragma unroll
    for (int p = 0; p < FPS_PAIRS; p++) {
        const int n0 = tid + (2 * p) * FPS_T;
        const int n1 = n0 + FPS_T;
        const float x0 = vb[n0],            x1 = vb[n1];
        const float y0 = vb[N_SZ + n0],     y1 = vb[N_SZ + n1];
        const float z0 = vb[2 * N_SZ + n0], z1 = vb[2 * N_SZ + n1];
        px[p] = (vf2){x0, x1};
        py[p] = (vf2){y0, y1};
        pz[p] = (vf2){z0, z1};
        dd[p] = (vf2){1e10f, 1e10f};
        sp[n0] = make_float4(x0, y0, z0, 0.0f);
        sp[n1] = make_float4(x1, y1, z1, 0.0f);
    }
    __syncthreads();

    int ci = 0;
    float4 c0 = sp[0];
    float cx = c0.x, cy = c0.y, cz = c0.z;

    for (int i = 0; i < NPOINT; i++) {
        if (tid == 0) scent[i] = ci;

        const vf2 cx2 = (vf2){cx, cx};
        const vf2 cy2 = (vf2){cy, cy};
        const vf2 cz2 = (vf2){cz, cz};

        float bv = -1.0f;
        int   bj = 0;
#pragma unroll
        for (int p = 0; p < FPS_PAIRS; p++) {
            const vf2 dx = px[p] - cx2;
            const vf2 dy = py[p] - cy2;
            const vf2 dz = pz[p] - cz2;
            vf2 s = dx * dx + dy * dy;   // contract off => mul,mul,add (exact)
            s = s + dz * dz;
            vf2 d;
            d.x = fminf(dd[p].x, s.x);
            d.y = fminf(dd[p].y, s.y);
            dd[p] = d;
            // strictly-greater keeps lowest index (j ascending => n ascending)
            if (d.x > bv) { bv = d.x; bj = 2 * p; }
            if (d.y > bv) { bv = d.y; bj = 2 * p + 1; }
        }
        // global point index n = tid + bj*512; low key = 4095 - n
        const unsigned n = (unsigned)(tid + (bj << 9));
        unsigned long long key =
            ((unsigned long long)__float_as_uint(bv) << 32) |
            (unsigned long long)(4095u - n);

        key = wave_kmax63(key);
        const int par = i & 1;
        if (lane == 63) ckey[par][wid] = key;
        __syncthreads();

        // all threads redundantly resolve the 8-way final (no 2nd barrier:
        // parity double-buffer makes the next write race-free)
        const ulonglong2* kb = (const ulonglong2*)(&ckey[par][0]);
        const ulonglong2 a0 = kb[0], a1 = kb[1], a2 = kb[2], a3 = kb[3];
        const unsigned long long m0 = kmax2(a0.x, a0.y);
        const unsigned long long m1 = kmax2(a1.x, a1.y);
        const unsigned long long m2 = kmax2(a2.x, a2.y);
        const unsigned long long m3 = kmax2(a3.x, a3.y);
        const unsigned long long kk = kmax2(kmax2(m0, m1), kmax2(m2, m3));

        ci = (int)(4095u - (unsigned)kk);
        const float4 c = sp[ci];
        cx = c.x; cy = c.y; cz = c.z;
    }
    __syncthreads();

    // epilogue: coalesced writes of cents + vertices_pool
    for (int i = tid; i < NPOINT; i += FPS_T) {
        const int cc = scent[i];
        const float4 v = sp[cc];
        cents[b * NPOINT + i] = cc;
        out_vp[(b * 3 + 0) * NPOINT + i] = v.x;
        out_vp[(b * 3 + 1) * NPOINT + i] = v.y;
        out_vp[(b * 3 + 2) * NPOINT + i] = v.z;
    }
}

// ---------------------------------------------------------------------------
// Kernel 3: gather+maxpool selected rows AND transpose to (B, C, NPOINT).
// 16 waves per block; wave w pools point j0+w (64 lanes x float2 = 128 ch),
// stages the 16x128 tile in LDS, then writes channel-major 64B segments.
// ---------------------------------------------------------------------------
#define GT_J 16
__global__ __launch_bounds__(1024) void pool_gather_t(
        const float* __restrict__ fmT,     // (B*N, C)
        const int* __restrict__ idx,       // (B*N*K), values in [0, B*N)
        const int* __restrict__ cents,     // (B*NPOINT)
        float* __restrict__ out_fp)        // (B, C, NPOINT)
{
    __shared__ float tile[C_SZ][GT_J + 1];
    const int tid  = threadIdx.x;
    const int lane = tid & 63;
    const int w    = tid >> 6;
    const int j0   = blockIdx.x * GT_J;    // global pooled-point base
    const int gp   = j0 + w;
    const int b    = gp >> 10;             // NPOINT = 1024
    const int ci   = cents[gp];
    const int* ip  = idx + ((size_t)(b * N_SZ + ci)) * K_SZ;
    const float2* src = (const float2*)fmT;

    float2 acc = make_float2(-INFINITY, -INFINITY);
#pragma unroll
    for (int k = 0; k < K_SZ; k++) {
        const int p = ip[k];
        const float2 v = src[(size_t)p * (C_SZ / 2) + lane];
        acc.x = fmaxf(acc.x, v.x);
        acc.y = fmaxf(acc.y, v.y);
    }
    tile[2 * lane][w]     = acc.x;
    tile[2 * lane + 1][w] = acc.y;
    __syncthreads();

    float* q = out_fp + (size_t)b * C_SZ * NPOINT + (j0 & (NPOINT - 1));
#pragma unroll
    for (int it = 0; it < 2; it++) {
        const int e  = tid + it * 1024;
        const int c  = e >> 4;
        const int jj = e & (GT_J - 1);
        q[(size_t)c * NPOINT + jj] = tile[c][jj];
    }
}

// ---------------------------------------------------------------------------
extern "C" void kernel_launch(void* const* d_in, const int* in_sizes, int n_in,
                              void* d_out, int out_size, void* d_ws, size_t ws_size,
                              hipStream_t stream) {
    const float* verts = (const float*)d_in[0];   // (B,3,N) f32
    const float* fm    = (const float*)d_in[1];   // (B,C,N) f32
    const int*   idx   = (const int*)d_in[2];     // (B*N*K) i32

    float* out    = (float*)d_out;
    float* out_vp = out;                               // B*3*NPOINT = 24576
    float* out_fp = out + (size_t)B_SZ * 3 * NPOINT;   // B*C*NPOINT

    char* ws = (char*)d_ws;
    float* fmT   = (float*)ws;                                     // 16 MB
    int*   cents = (int*)(ws + (size_t)B_SZ * N_SZ * C_SZ * 4);    // 32 KB

    dim3 tb(32, 8);
    transpose_fm<<<dim3(N_SZ / 32, C_SZ / 32, B_SZ), tb, 0, stream>>>(fm, fmT);
    fps_kernel<<<B_SZ, FPS_T, 0, stream>>>(verts, out_vp, cents);
    pool_gather_t<<<(B_SZ * NPOINT) / GT_J, 1024, 0, stream>>>(fmT, idx, cents, out_fp);
}